// Round 2
// baseline (5394.481 us; speedup 1.0000x reference)
//
#include <hip/hip_runtime.h>

#define B_ 16
#define S_ 4096
#define D_ 256
#define H_ 256
#define CHUNK 64            // xp steps staged per global_load_lds batch
#define NCHUNK (S_ / CHUNK)

typedef _Float16 h2 __attribute__((ext_vector_type(2)));
typedef _Float16 h8 __attribute__((ext_vector_type(8)));
typedef float f4 __attribute__((ext_vector_type(4)));

#if defined(__has_builtin)
#if __has_builtin(__builtin_amdgcn_fdot2)
#define HAVE_FDOT2 1
#endif
#endif

static __device__ __forceinline__ float fdot2f(h2 a, h2 b, float c) {
#ifdef HAVE_FDOT2
    return __builtin_amdgcn_fdot2(a, b, c, false);
#else
    float d = c;
    asm("v_dot2_f32_f16 %0, %1, %2, %0" : "+v"(d) : "v"(a), "v"(b));
    return d;
#endif
}

// async global->LDS, 16B per lane (wave-uniform LDS base + lane*16 implicit)
static __device__ __forceinline__ void gload_lds16(const float* g, float* l) {
    __builtin_amdgcn_global_load_lds(
        (const __attribute__((address_space(1))) unsigned int*)g,
        (__attribute__((address_space(3))) unsigned int*)l,
        16, 0, 0);
}

// Kernel 1: xp[r][h] = sum_d x[r][d] * Wx[d][h] + bias[h], written into d_out.
__global__ __launch_bounds__(256) void xproj_kernel(
    const float* __restrict__ x, const float* __restrict__ Wx,
    const float* __restrict__ bias, float* __restrict__ out)
{
    __shared__ float xs[32 * 256];
    const int tid = threadIdx.x;
    const long long row0 = (long long)blockIdx.x * 32;

    {
        const f4* __restrict__ xg = (const f4*)(x + row0 * D_);
        f4* xsv = (f4*)xs;
        #pragma unroll
        for (int k = 0; k < 8; ++k)
            xsv[tid + k * 256] = xg[tid + k * 256];
    }
    __syncthreads();

    const int j = tid;
    float acc[32];
    const float bj = bias[j];
    #pragma unroll
    for (int r = 0; r < 32; ++r) acc[r] = bj;

    for (int d4 = 0; d4 < D_ / 4; ++d4) {
        const float w0 = Wx[(d4 * 4 + 0) * H_ + j];
        const float w1 = Wx[(d4 * 4 + 1) * H_ + j];
        const float w2 = Wx[(d4 * 4 + 2) * H_ + j];
        const float w3 = Wx[(d4 * 4 + 3) * H_ + j];
        #pragma unroll
        for (int r = 0; r < 32; ++r) {
            f4 xv = *(const f4*)&xs[r * 256 + d4 * 4];
            acc[r] = fmaf(xv.x, w0, acc[r]);
            acc[r] = fmaf(xv.y, w1, acc[r]);
            acc[r] = fmaf(xv.z, w2, acc[r]);
            acc[r] = fmaf(xv.w, w3, acc[r]);
        }
    }
    #pragma unroll
    for (int r = 0; r < 32; ++r)
        out[(row0 + r) * H_ + j] = acc[r];
}

// Kernel 2: sequential scan, one block (CU) per batch.
// xp staged in 64-step chunks via global_load_lds (double-buffered LDS);
// main loop has NO global loads — only ds_read + dot2 + one barrier/step.
__global__ __launch_bounds__(256, 1) void scan_kernel(
    const float* __restrict__ Wh, const float* __restrict__ state0,
    float* __restrict__ out)
{
    __shared__ __align__(16) _Float16 hbuf[2][H_];
    __shared__ __align__(16) float xs[2][CHUNK * H_];   // 2 x 64KB
    const int j = threadIdx.x;
    const int wid = j >> 6;
    const int b = blockIdx.x;

    // Wh column j -> fp16 pairs in registers
    h2 w[128];
    #pragma unroll
    for (int i = 0; i < 128; ++i) {
        float wa = Wh[(2 * i)     * H_ + j];
        float wb = Wh[(2 * i + 1) * H_ + j];
        h2 p;
        p[0] = (_Float16)wa;
        p[1] = (_Float16)wb;
        w[i] = p;
    }

    hbuf[0][j] = (_Float16)state0[b * H_ + j];

    float* __restrict__ outb = out + (long long)b * S_ * H_;

    // stage chunk 0 (each wave stages rows wid, wid+4, ... : 16 rows/wave)
    #pragma unroll
    for (int k = 0; k < CHUNK / 4; ++k) {
        const int r = wid + 4 * k;
        gload_lds16(outb + (long long)r * H_ + (j & 63) * 4, &xs[0][r * H_]);
    }
    asm volatile("s_waitcnt vmcnt(0)" ::: "memory");
    __syncthreads();

    for (int c = 0; c < NCHUNK; ++c) {
        const int buf = c & 1;
        // issue async loads for next chunk into the other buffer
        if (c + 1 < NCHUNK) {
            const long long t0 = (long long)(c + 1) * CHUNK;
            #pragma unroll
            for (int k = 0; k < CHUNK / 4; ++k) {
                const int r = wid + 4 * k;
                gload_lds16(outb + (t0 + r) * H_ + (j & 63) * 4,
                            &xs[buf ^ 1][r * H_]);
            }
        }

        for (int s = 0; s < CHUNK; ++s) {
            const int t = c * CHUNK + s;
            const int p = t & 1;
            const float xpv = xs[buf][s * H_ + j];   // conflict-free ds_read_b32

            float a[8];
            #pragma unroll
            for (int i = 0; i < 8; ++i) a[i] = 0.f;
            #pragma unroll
            for (int cc = 0; cc < 32; ++cc) {
                h8 hv = *(const h8*)&hbuf[p][cc * 8];   // 16B LDS broadcast
                union { h8 v; h2 q[4]; } u;
                u.v = hv;
                const int base = (cc & 1) * 4;
                a[base + 0] = fdot2f(u.q[0], w[cc * 4 + 0], a[base + 0]);
                a[base + 1] = fdot2f(u.q[1], w[cc * 4 + 1], a[base + 1]);
                a[base + 2] = fdot2f(u.q[2], w[cc * 4 + 2], a[base + 2]);
                a[base + 3] = fdot2f(u.q[3], w[cc * 4 + 3], a[base + 3]);
            }
            const float pre = (((a[0] + a[4]) + (a[1] + a[5])) +
                               ((a[2] + a[6]) + (a[3] + a[7]))) + xpv;
            // tanh(x) = 1 - 2/(exp2(2*log2(e)*x) + 1)
            const float e = __builtin_amdgcn_exp2f(pre * 2.8853900817779268f);
            const float hn = 1.f - 2.f / (e + 1.f);

            hbuf[p ^ 1][j] = (_Float16)hn;             // publish h for t+1
            outb[(long long)t * H_ + j] = hn;          // fire-and-forget store
            __syncthreads();
        }

        // next chunk's buffer must be fully landed before use
        if (c + 1 < NCHUNK) {
            asm volatile("s_waitcnt vmcnt(0)" ::: "memory");
            __syncthreads();
        }
    }
}

extern "C" void kernel_launch(void* const* d_in, const int* in_sizes, int n_in,
                              void* d_out, int out_size, void* d_ws, size_t ws_size,
                              hipStream_t stream) {
    const float* x  = (const float*)d_in[0];   // [B,S,D]
    const float* s0 = (const float*)d_in[1];   // [B,H]
    const float* Wx = (const float*)d_in[2];   // [D,H]
    const float* Wh = (const float*)d_in[3];   // [H,H]
    const float* bv = (const float*)d_in[4];   // [H]
    float* out = (float*)d_out;                // [B,S,H]

    xproj_kernel<<<dim3((B_ * S_) / 32), dim3(256), 0, stream>>>(x, Wx, bv, out);
    scan_kernel<<<dim3(B_), dim3(256), 0, stream>>>(Wh, s0, out);
}

// Round 4
// 1871.626 us; speedup vs baseline: 2.8822x; 2.8822x over previous
//
#include <hip/hip_runtime.h>

#define B_ 16
#define S_ 4096
#define D_ 256
#define H_ 256

typedef _Float16 h2 __attribute__((ext_vector_type(2)));
typedef _Float16 h8 __attribute__((ext_vector_type(8)));
typedef float f4 __attribute__((ext_vector_type(4)));

static __device__ __forceinline__ float fdot2f(h2 a, h2 b, float c) {
    return __builtin_amdgcn_fdot2(a, b, c, false);
}

// pure-VALU cross-lane via DPP quad_perm (no LDS pipe); ctrl must be ICE
template <int CTRL>
static __device__ __forceinline__ float dpp_qp(float v) {
    int r = __builtin_amdgcn_update_dpp(0, __float_as_int(v), CTRL, 0xF, 0xF, true);
    return __int_as_float(r);
}
#define DPP_XOR1 0xB1   // quad_perm [1,0,3,2]
#define DPP_XOR2 0x4E   // quad_perm [2,3,0,1]

// swizzled f16-index for h element i in a 256-entry LDS buffer:
// slice s=i>>6 (128B block), chunk r=(i>>3)&7 (16B), XOR-placed so the 4
// distinct addresses of a distributed read hit disjoint bank quads.
static __device__ __forceinline__ int swz(int i) {
    const int s = i >> 6, r = (i >> 3) & 7, e = i & 7;
    return 64 * s + 8 * ((r + 2 * s) & 7) + e;
}

// Kernel 1: xp[r][h] = sum_d x[r][d] * Wx[d][h] + bias[h], written into d_out.
__global__ __launch_bounds__(256) void xproj_kernel(
    const float* __restrict__ x, const float* __restrict__ Wx,
    const float* __restrict__ bias, float* __restrict__ out)
{
    __shared__ float xs[32 * 256];
    const int tid = threadIdx.x;
    const long long row0 = (long long)blockIdx.x * 32;

    {
        const f4* __restrict__ xg = (const f4*)(x + row0 * D_);
        f4* xsv = (f4*)xs;
        #pragma unroll
        for (int k = 0; k < 8; ++k)
            xsv[tid + k * 256] = xg[tid + k * 256];
    }
    __syncthreads();

    const int j = tid;
    float acc[32];
    const float bj = bias[j];
    #pragma unroll
    for (int r = 0; r < 32; ++r) acc[r] = bj;

    for (int d4 = 0; d4 < D_ / 4; ++d4) {
        const float w0 = Wx[(d4 * 4 + 0) * H_ + j];
        const float w1 = Wx[(d4 * 4 + 1) * H_ + j];
        const float w2 = Wx[(d4 * 4 + 2) * H_ + j];
        const float w3 = Wx[(d4 * 4 + 3) * H_ + j];
        #pragma unroll
        for (int r = 0; r < 32; ++r) {
            f4 xv = *(const f4*)&xs[r * 256 + d4 * 4];
            acc[r] = fmaf(xv.x, w0, acc[r]);
            acc[r] = fmaf(xv.y, w1, acc[r]);
            acc[r] = fmaf(xv.z, w2, acc[r]);
            acc[r] = fmaf(xv.w, w3, acc[r]);
        }
    }
    #pragma unroll
    for (int r = 0; r < 32; ++r)
        out[(row0 + r) * H_ + j] = acc[r];
}

// Kernel 2: sequential scan, one block (CU) per batch, 256 threads.
// Split-K x4: thread t -> 4 outputs j in [4q,4q+4) (q=t>>2) over i-slice
// s=t&3 (64 i's). h read DISTRIBUTED from swizzled LDS (8 b128/lane),
// partials reduced with DPP quad_perm butterflies (VALU only). Final
// owner: thread t owns j == t. xp via register prefetch ring (dist 4).
__global__ __launch_bounds__(256, 1) void scan_kernel(
    const float* __restrict__ Wh, const float* __restrict__ state0,
    float* __restrict__ out)
{
    __shared__ __align__(16) _Float16 hbuf[2][H_];
    const int tid = threadIdx.x;
    const int s = tid & 3;          // i-slice
    const int q = tid >> 2;         // j-group
    const int b = blockIdx.x;
    const bool o1 = (s & 1) != 0;
    const bool o2 = (s & 2) != 0;

    // W[i][j] for i in [64s,64s+64), j in [4q,4q+4), packed as h2 i-pairs.
    h2 w[4][32];
    #pragma unroll
    for (int jj = 0; jj < 4; ++jj) {
        const int j = 4 * q + jj;
        #pragma unroll
        for (int ii = 0; ii < 32; ++ii) {
            const int i = 64 * s + 2 * ii;
            h2 p;
            p[0] = (_Float16)Wh[(long long)i * H_ + j];
            p[1] = (_Float16)Wh[(long long)(i + 1) * H_ + j];
            w[jj][ii] = p;
        }
    }

    hbuf[0][swz(tid)] = (_Float16)state0[b * H_ + tid];

    float* __restrict__ outb = out + (long long)b * S_ * H_;

    // xp prefetch ring, distance 4 (static indices via unroll-4)
    float xr[4];
    #pragma unroll
    for (int k = 0; k < 4; ++k)
        xr[k] = outb[(long long)k * H_ + tid];
    __syncthreads();

    // chunk r holds h[64s+8r .. +8] at f16-pos 64s + 8*((r+2s)&7)
    #pragma unroll 4
    for (int st = 0; st < S_; ++st) {
        const int p = st & 1;
        const _Float16* hb = hbuf[p];

        h8 hv[8];
        #pragma unroll
        for (int r = 0; r < 8; ++r)
            hv[r] = *(const h8*)&hb[64 * s + 8 * ((r + 2 * s) & 7)];

        float acc0 = 0.f, acc1 = 0.f, acc2 = 0.f, acc3 = 0.f;
        #pragma unroll
        for (int r = 0; r < 8; ++r) {
            union { h8 v; h2 pr[4]; } u;
            u.v = hv[r];
            #pragma unroll
            for (int m = 0; m < 4; ++m) {
                const int ii = 4 * r + m;
                acc0 = fdot2f(u.pr[m], w[0][ii], acc0);
                acc1 = fdot2f(u.pr[m], w[1][ii], acc1);
                acc2 = fdot2f(u.pr[m], w[2][ii], acc2);
                acc3 = fdot2f(u.pr[m], w[3][ii], acc3);
            }
        }

        // reduce-scatter across the 4 slice-threads (pure VALU DPP)
        // round 1 (xor1): keep parity o1, send parity !o1
        float vA = o1 ? acc1 : acc0;      // kept jj in {o1, 2+o1}
        float vB = o1 ? acc3 : acc2;
        float sA = o1 ? acc0 : acc1;      // partner keeps these
        float sB = o1 ? acc2 : acc3;
        vA += dpp_qp<DPP_XOR1>(sA);
        vB += dpp_qp<DPP_XOR1>(sB);
        // round 2 (xor2): keep (jj&2)==s&2
        float v   = o2 ? vB : vA;
        float snd = o2 ? vA : vB;
        v += dpp_qp<DPP_XOR2>(snd);
        // v = full dot for j = 4q + s = tid

        const float pre = v + xr[st & 3];
        const float e = __builtin_amdgcn_exp2f(pre * 2.8853900817779268f);
        const float hn = fmaf(-2.f, __builtin_amdgcn_rcpf(e + 1.f), 1.f);

        outb[(long long)st * H_ + tid] = hn;       // fire-and-forget store
        hbuf[p ^ 1][swz(tid)] = (_Float16)hn;      // publish h for t+1

        const int nt = st + 4;
        xr[st & 3] = (nt < S_) ? outb[(long long)nt * H_ + tid] : 0.f;
        __syncthreads();
    }
}

extern "C" void kernel_launch(void* const* d_in, const int* in_sizes, int n_in,
                              void* d_out, int out_size, void* d_ws, size_t ws_size,
                              hipStream_t stream) {
    const float* x  = (const float*)d_in[0];   // [B,S,D]
    const float* s0 = (const float*)d_in[1];   // [B,H]
    const float* Wx = (const float*)d_in[2];   // [D,H]
    const float* Wh = (const float*)d_in[3];   // [H,H]
    const float* bv = (const float*)d_in[4];   // [H]
    float* out = (float*)d_out;                // [B,S,H]

    xproj_kernel<<<dim3((B_ * S_) / 32), dim3(256), 0, stream>>>(x, Wx, bv, out);
    scan_kernel<<<dim3(B_), dim3(256), 0, stream>>>(Wh, s0, out);
}